// Round 16
// baseline (986.653 us; speedup 1.0000x reference)
//
#include <hip/hip_runtime.h>
#include <math.h>

#define Bn 32
#define Mn 2048
#define Nn 65536      // Bn * Mn
#define SDn 16
#define CWn 512
#define EPSf 1e-5f
#define KGF 8
#define LSC 2048.0f   // lo-plane scale (2^11)
#define LSCI (1.0f / 2048.0f)

typedef unsigned short u16;
typedef _Float16 fp16_t;
typedef __attribute__((ext_vector_type(8))) _Float16 h8v;  // MFMA A/B frag: 8 f16
typedef __attribute__((ext_vector_type(4))) float f4v;     // MFMA C/D frag: 4 fp32

__device__ __forceinline__ u16 f2h(float f) {
    union { fp16_t h; u16 u; } c; c.h = (fp16_t)f; return c.u;
}
__device__ __forceinline__ float h2f(u16 u) {
    union { fp16_t h; u16 u; } c; c.u = u; return (float)c.h;
}
__device__ __forceinline__ void fsplit(float f, u16& hi, u16& lo) {
    hi = f2h(f);
    lo = f2h((f - h2f(hi)) * LSC);
}
__device__ __forceinline__ float fjoin(u16 hi, u16 lo) {
    return h2f(hi) + h2f(lo) * LSCI;
}
// async global->LDS, 16 bytes/lane (dest must be wave-uniform base + lane*16)
__device__ __forceinline__ void gll16(const u16* g, u16* l) {
    __builtin_amdgcn_global_load_lds((const __attribute__((address_space(1))) void*)g,
                                     (__attribute__((address_space(3))) void*)l, 16, 0, 0);
}
// lexicographic comparator swap (merge tail): keep (d0,i0) <= (d1,i1)
__device__ __forceinline__ void cswap(float& d0, int& i0, float& d1, int& i1) {
    const bool gt = (d0 > d1) || (d0 == d1 && i0 > i1);
    const float ta = gt ? d1 : d0, tb = gt ? d0 : d1;
    const int   ua = gt ? i1 : i0, ub = gt ? i0 : i1;
    d0 = ta; d1 = tb; i0 = ua; i1 = ub;
}
// distance-only stable comparator swap (hot loop): swap iff d0 > d1 strictly
__device__ __forceinline__ void cswapd(float& d0, int& i0, float& d1, int& i1) {
    const bool gt = d0 > d1;
    const float ta = gt ? d1 : d0, tb = gt ? d0 : d1;
    const int   ua = gt ? i1 : i0, ub = gt ? i0 : i1;
    d0 = ta; d1 = tb; i0 = ua; i1 = ub;
}

// ============================================================================
// prep: m1/m2 weights -> split layout, normalize s -> xs, zero stats (fused)
// ============================================================================
__global__ __launch_bounds__(256) void prep_kernel(
    const float* __restrict__ wm1, const float* __restrict__ wm2,
    const float* __restrict__ s,
    u16* __restrict__ wbuf1, u16* __restrict__ xs, float* __restrict__ stats)
{
    const int bid = blockIdx.x;
    const int tid = threadIdx.x;
    if (bid < 544) {
        int i = bid * 256 + tid;          // logical: 8192 (m1 pad) + 131072 (m2)
        float w; int r, k, Cin; size_t base;
        if (i < 8192) {                   // m1 padded [256][32]
            r = i >> 5; k = i & 31; Cin = 32; base = 0;
            w = (k < SDn) ? wm1[r * SDn + k] : 0.f;
        } else {
            int j = i - 8192;
            r = j >> 8; k = j & 255; Cin = 256; base = 16384;
            w = wm2[j];
        }
        const size_t addr = base + (size_t)r * (2 * Cin) + k;
        u16 hi, lo; fsplit(w, hi, lo);
        wbuf1[addr] = hi;
        wbuf1[addr + Cin] = lo;
    } else if (bid < 800) {
        // ---- normalize s[B,16,M] -> xs[N][64] (hi[32]|lo[32], upper 16 zero)
        const int b2 = bid - 544;
        const int m = (b2 & 7) * 256 + tid;
        const int b = b2 >> 3;
        const float* sp = s + (size_t)b * SDn * Mn + m;
        float v[SDn]; float sq = 0.f;
#pragma unroll
        for (int c = 0; c < SDn; ++c) { v[c] = sp[(size_t)c * Mn]; sq += v[c] * v[c]; }
        const float r = 1.0f / sqrtf(sq);
        unsigned int uh[8], ul[8];
#pragma unroll
        for (int c = 0; c < 8; ++c) {
            u16 h0, l0, h1, l1;
            fsplit(v[2 * c] * r, h0, l0);
            fsplit(v[2 * c + 1] * r, h1, l1);
            uh[c] = (unsigned int)h0 | ((unsigned int)h1 << 16);
            ul[c] = (unsigned int)l0 | ((unsigned int)l1 << 16);
        }
        uint4* xp = (uint4*)(xs + (size_t)(b * Mn + m) * 64);
        xp[0] = make_uint4(uh[0], uh[1], uh[2], uh[3]);
        xp[1] = make_uint4(uh[4], uh[5], uh[6], uh[7]);
        xp[2] = make_uint4(0, 0, 0, 0);
        xp[3] = make_uint4(0, 0, 0, 0);
        xp[4] = make_uint4(ul[0], ul[1], ul[2], ul[3]);
        xp[5] = make_uint4(ul[4], ul[5], ul[6], ul[7]);
        xp[6] = make_uint4(0, 0, 0, 0);
        xp[7] = make_uint4(0, 0, 0, 0);
    } else {
        // ---- zero BN stats (4096 floats) ----
        float4 z4 = {0.f, 0.f, 0.f, 0.f};
        float4* sp4 = (float4*)stats;
#pragma unroll
        for (int k = 0; k < 4; ++k) sp4[tid * 4 + k] = z4;
    }
}

// ---- wcvt2: c1/c2/c3 weights -> split layout (runs after c0) ---------------
__global__ __launch_bounds__(256) void wcvt2_kernel(
    const float* __restrict__ wc1, const float* __restrict__ wc2,
    const float* __restrict__ wc3, u16* __restrict__ wbuf2)
{
    int i = blockIdx.x * 256 + threadIdx.x;   // 131072 + 32768 + 8192 logical
    float w; int r, k, Cin; size_t base;
    if (i < 131072)                   { r = i >> 9; k = i & 511; Cin = 512; base = 0;      w = wc1[i]; }
    else if ((i -= 131072) < 32768)   { r = i >> 8; k = i & 255; Cin = 256; base = 262144; w = wc2[i]; }
    else { i -= 32768;                  r = i >> 7; k = i & 127; Cin = 128; base = 327680; w = wc3[i]; }
    const size_t addr = base + (size_t)r * (2 * Cin) + k;
    u16 hi, lo; fsplit(w, hi, lo);
    wbuf2[addr] = hi;
    wbuf2[addr + Cin] = lo;
}

// ---- split fp16 MFMA GEMM, async staging, XCD remap, swizzled LDS ----------
// acc0 = Wh*Xh ; accL = Wh*Xl' + Wl'*Xh ; result = acc0 + accL/2048
template<int RW, int CWv, int EPI, int MY>
__global__ __launch_bounds__(256) void mfma_gemm(
    const u16* __restrict__ W, const u16* __restrict__ X, u16* __restrict__ Y,
    const float* __restrict__ bias, const float* __restrict__ zmod,
    float* __restrict__ stats, int Cout, int Cin)
{
    constexpr int BM = RW * 64, BN = CWv * 64;
    constexpr int ASEG = BM / 64, BSEG = BN / 64;
    constexpr int LMY = (MY == 1) ? 0 : (MY == 2) ? 1 : (MY == 4) ? 2 : 3;
    __shared__ __align__(16) u16 Ah[BM * 32], Al[BM * 32];
    __shared__ __align__(16) u16 Bh[BN * 32], Bl[BN * 32];
    __shared__ float sstat[(EPI == 2) ? (CWv * BM * 2) : 1];

    const int tid = threadIdx.x;
    const int wave = tid >> 6;
    const int lane = tid & 63;
    const int wm = wave & (RW - 1), wn = wave / RW;
    const int l15 = lane & 15, q = lane >> 4;
    const int lin = blockIdx.x;
    const int xcd = lin & 7;
    const int jj = lin >> 3;
    const int m0 = (jj & (MY - 1)) * BM;
    const int n0 = (xcd + ((jj >> LMY) << 3)) * BN;
    const int SW = 2 * Cin;

    f4v acc0[4][4], accL[4][4];
#pragma unroll
    for (int i = 0; i < 4; ++i)
#pragma unroll
        for (int j = 0; j < 4; ++j) {
            acc0[i][j] = (f4v){0.f, 0.f, 0.f, 0.f};
            accL[i][j] = (f4v){0.f, 0.f, 0.f, 0.f};
        }

    const int nsteps = Cin >> 5;
    for (int ks = 0; ks < nsteps; ++ks) {
        const int k0 = ks << 5;
        __syncthreads();   // previous iteration's frag reads done before overwrite
#pragma unroll
        for (int s = 0; s < ASEG; ++s) {
            const int flat = s * 256 + tid;
            const int row = flat >> 2;
            const int qs = (flat & 3) ^ ((row >> 1) & 3);   // swizzled source chunk
            const u16* ga = W + (size_t)(m0 + row) * SW + k0 + qs * 8;
            gll16(ga, Ah + flat * 8);
            gll16(ga + Cin, Al + flat * 8);
        }
#pragma unroll
        for (int s = 0; s < BSEG; ++s) {
            const int flat = s * 256 + tid;
            const int row = flat >> 2;
            const int qs = (flat & 3) ^ ((row >> 1) & 3);
            const u16* gb = X + (size_t)(n0 + row) * SW + k0 + qs * 8;
            gll16(gb, Bh + flat * 8);
            gll16(gb + Cin, Bl + flat * 8);
        }
        __syncthreads();   // drains vmcnt -> LDS tiles ready
        h8v afh[4], afl[4], bfh[4], bfl[4];
#pragma unroll
        for (int i = 0; i < 4; ++i) {
            const int ar = wm * 64 + i * 16 + l15;
            const int ao = ar * 32 + ((q ^ ((ar >> 1) & 3)) << 3);
            afh[i] = *(const h8v*)(Ah + ao);
            afl[i] = *(const h8v*)(Al + ao);
        }
#pragma unroll
        for (int j = 0; j < 4; ++j) {
            const int br = wn * 64 + j * 16 + l15;
            const int bo = br * 32 + ((q ^ ((br >> 1) & 3)) << 3);
            bfh[j] = *(const h8v*)(Bh + bo);
            bfl[j] = *(const h8v*)(Bl + bo);
        }
#pragma unroll
        for (int i = 0; i < 4; ++i)
#pragma unroll
            for (int j = 0; j < 4; ++j) {
                accL[i][j] = __builtin_amdgcn_mfma_f32_16x16x32_f16(afh[i], bfl[j], accL[i][j], 0, 0, 0);
                accL[i][j] = __builtin_amdgcn_mfma_f32_16x16x32_f16(afl[i], bfh[j], accL[i][j], 0, 0, 0);
                acc0[i][j] = __builtin_amdgcn_mfma_f32_16x16x32_f16(afh[i], bfh[j], acc0[i][j], 0, 0, 0);
            }
    }

    // ---- epilogue ----
    const int bb = n0 >> 11;
    const int SY = 2 * Cout;
#pragma unroll
    for (int i = 0; i < 4; ++i) {
        const int chb = m0 + wm * 64 + i * 16 + q * 4;
        const float4 bias4 = *(const float4*)(bias + chb);
        float z0 = 0.f, z1 = 0.f, z2 = 0.f, z3 = 0.f;
        if constexpr (EPI == 1) {
            const float4 z4 = *(const float4*)(zmod + bb * CWn + chb);
            z0 = z4.x; z1 = z4.y; z2 = z4.z; z3 = z4.w;
        }
        float ssum[4] = {0.f, 0.f, 0.f, 0.f}, ssq[4] = {0.f, 0.f, 0.f, 0.f};
#pragma unroll
        for (int j = 0; j < 4; ++j) {
            const int n = n0 + wn * 64 + j * 16 + l15;
            float v0 = fmaf(accL[i][j][0], LSCI, acc0[i][j][0]) + bias4.x;
            float v1 = fmaf(accL[i][j][1], LSCI, acc0[i][j][1]) + bias4.y;
            float v2 = fmaf(accL[i][j][2], LSCI, acc0[i][j][2]) + bias4.z;
            float v3 = fmaf(accL[i][j][3], LSCI, acc0[i][j][3]) + bias4.w;
            if constexpr (EPI == 0) {
                v0 = fmaxf(v0, 0.f); v1 = fmaxf(v1, 0.f); v2 = fmaxf(v2, 0.f); v3 = fmaxf(v3, 0.f);
            } else if constexpr (EPI == 1) {
                v0 = fminf(fmaxf(v0, -1.f), 1.f) * z0;
                v1 = fminf(fmaxf(v1, -1.f), 1.f) * z1;
                v2 = fminf(fmaxf(v2, -1.f), 1.f) * z2;
                v3 = fminf(fmaxf(v3, -1.f), 1.f) * z3;
            } else {
                ssum[0] += v0; ssum[1] += v1; ssum[2] += v2; ssum[3] += v3;
                ssq[0] += v0 * v0; ssq[1] += v1 * v1; ssq[2] += v2 * v2; ssq[3] += v3 * v3;
            }
            u16 h0, l0, h1, l1, h2, l2, h3, l3;
            fsplit(v0, h0, l0); fsplit(v1, h1, l1);
            fsplit(v2, h2, l2); fsplit(v3, h3, l3);
            ushort4 hv = {h0, h1, h2, h3};
            ushort4 lv = {l0, l1, l2, l3};
            u16* yp = Y + (size_t)n * SY + chb;
            *(ushort4*)yp = hv;
            *(ushort4*)(yp + Cout) = lv;
        }
        if constexpr (EPI == 2) {
#pragma unroll
            for (int r = 0; r < 4; ++r) {
#pragma unroll
                for (int d = 1; d < 16; d <<= 1) {
                    ssum[r] += __shfl_xor(ssum[r], d);
                    ssq[r]  += __shfl_xor(ssq[r], d);
                }
            }
            if (l15 == 0) {
                const int chl = wm * 64 + i * 16 + q * 4;
#pragma unroll
                for (int r = 0; r < 4; ++r) {
                    sstat[(wn * BM + chl + r) * 2]     = ssum[r];
                    sstat[(wn * BM + chl + r) * 2 + 1] = ssq[r];
                }
            }
        }
    }
    if constexpr (EPI == 2) {
        __syncthreads();
        if (tid < BM) {
            float s0 = 0.f, s1 = 0.f;
#pragma unroll
            for (int w = 0; w < CWv; ++w) {
                s0 += sstat[(w * BM + tid) * 2];
                s1 += sstat[(w * BM + tid) * 2 + 1];
            }
            atomicAdd(&stats[(m0 + tid) * 2], s0);
            atomicAdd(&stats[(m0 + tid) * 2 + 1], s1);
        }
    }
}

// ---- c0 variant: A staged from fp32 W (d_in) with IN-KERNEL split ----------
// Identical planes to wcvt+gll16 (same fsplit); frees scratch so x2 and y0
// are fully disjoint -> c0 runs as ONE race-free launch. B path unchanged.
template<int RW, int CWv, int MY>
__global__ __launch_bounds__(256) void mfma_gemm_wf(
    const float* __restrict__ Wf, const u16* __restrict__ X, u16* __restrict__ Y,
    const float* __restrict__ bias, float* __restrict__ stats, int Cout, int Cin)
{
    constexpr int BM = RW * 64, BN = CWv * 64;
    constexpr int ASEG = BM / 64, BSEG = BN / 64;
    constexpr int LMY = (MY == 1) ? 0 : (MY == 2) ? 1 : (MY == 4) ? 2 : 3;
    __shared__ __align__(16) u16 Ah[BM * 32], Al[BM * 32];
    __shared__ __align__(16) u16 Bh[BN * 32], Bl[BN * 32];
    __shared__ float sstat[CWv * BM * 2];

    const int tid = threadIdx.x;
    const int wave = tid >> 6;
    const int lane = tid & 63;
    const int wm = wave & (RW - 1), wn = wave / RW;
    const int l15 = lane & 15, q = lane >> 4;
    const int lin = blockIdx.x;
    const int xcd = lin & 7;
    const int jj = lin >> 3;
    const int m0 = (jj & (MY - 1)) * BM;
    const int n0 = (xcd + ((jj >> LMY) << 3)) * BN;
    const int SW = 2 * Cin;

    f4v acc0[4][4], accL[4][4];
#pragma unroll
    for (int i = 0; i < 4; ++i)
#pragma unroll
        for (int j = 0; j < 4; ++j) {
            acc0[i][j] = (f4v){0.f, 0.f, 0.f, 0.f};
            accL[i][j] = (f4v){0.f, 0.f, 0.f, 0.f};
        }

    const int nsteps = Cin >> 5;
    for (int ks = 0; ks < nsteps; ++ks) {
        const int k0 = ks << 5;
        __syncthreads();
#pragma unroll
        for (int s = 0; s < BSEG; ++s) {
            const int flat = s * 256 + tid;
            const int row = flat >> 2;
            const int qs = (flat & 3) ^ ((row >> 1) & 3);
            const u16* gb = X + (size_t)(n0 + row) * SW + k0 + qs * 8;
            gll16(gb, Bh + flat * 8);
            gll16(gb + Cin, Bl + flat * 8);
        }
#pragma unroll
        for (int s = 0; s < ASEG; ++s) {
            const int flat = s * 256 + tid;
            const int row = flat >> 2;
            const int qs = (flat & 3) ^ ((row >> 1) & 3);
            const float* gw = Wf + (size_t)(m0 + row) * Cin + k0 + qs * 8;
            const float4 wa = *(const float4*)gw;
            const float4 wb = *(const float4*)(gw + 4);
            const float wv[8] = {wa.x, wa.y, wa.z, wa.w, wb.x, wb.y, wb.z, wb.w};
            unsigned hv[4], lv[4];
#pragma unroll
            for (int e = 0; e < 4; ++e) {
                u16 h0, l0, h1, l1;
                fsplit(wv[2 * e], h0, l0);
                fsplit(wv[2 * e + 1], h1, l1);
                hv[e] = (unsigned)h0 | ((unsigned)h1 << 16);
                lv[e] = (unsigned)l0 | ((unsigned)l1 << 16);
            }
            *(uint4*)(Ah + flat * 8) = make_uint4(hv[0], hv[1], hv[2], hv[3]);
            *(uint4*)(Al + flat * 8) = make_uint4(lv[0], lv[1], lv[2], lv[3]);
        }
        __syncthreads();
        h8v afh[4], afl[4], bfh[4], bfl[4];
#pragma unroll
        for (int i = 0; i < 4; ++i) {
            const int ar = wm * 64 + i * 16 + l15;
            const int ao = ar * 32 + ((q ^ ((ar >> 1) & 3)) << 3);
            afh[i] = *(const h8v*)(Ah + ao);
            afl[i] = *(const h8v*)(Al + ao);
        }
#pragma unroll
        for (int j = 0; j < 4; ++j) {
            const int br = wn * 64 + j * 16 + l15;
            const int bo = br * 32 + ((q ^ ((br >> 1) & 3)) << 3);
            bfh[j] = *(const h8v*)(Bh + bo);
            bfl[j] = *(const h8v*)(Bl + bo);
        }
#pragma unroll
        for (int i = 0; i < 4; ++i)
#pragma unroll
            for (int j = 0; j < 4; ++j) {
                accL[i][j] = __builtin_amdgcn_mfma_f32_16x16x32_f16(afh[i], bfl[j], accL[i][j], 0, 0, 0);
                accL[i][j] = __builtin_amdgcn_mfma_f32_16x16x32_f16(afl[i], bfh[j], accL[i][j], 0, 0, 0);
                acc0[i][j] = __builtin_amdgcn_mfma_f32_16x16x32_f16(afh[i], bfh[j], acc0[i][j], 0, 0, 0);
            }
    }

    // ---- epilogue (EPI=2: raw + stats) ----
    const int SY = 2 * Cout;
#pragma unroll
    for (int i = 0; i < 4; ++i) {
        const int chb = m0 + wm * 64 + i * 16 + q * 4;
        const float4 bias4 = *(const float4*)(bias + chb);
        float ssum[4] = {0.f, 0.f, 0.f, 0.f}, ssq[4] = {0.f, 0.f, 0.f, 0.f};
#pragma unroll
        for (int j = 0; j < 4; ++j) {
            const int n = n0 + wn * 64 + j * 16 + l15;
            float v0 = fmaf(accL[i][j][0], LSCI, acc0[i][j][0]) + bias4.x;
            float v1 = fmaf(accL[i][j][1], LSCI, acc0[i][j][1]) + bias4.y;
            float v2 = fmaf(accL[i][j][2], LSCI, acc0[i][j][2]) + bias4.z;
            float v3 = fmaf(accL[i][j][3], LSCI, acc0[i][j][3]) + bias4.w;
            ssum[0] += v0; ssum[1] += v1; ssum[2] += v2; ssum[3] += v3;
            ssq[0] += v0 * v0; ssq[1] += v1 * v1; ssq[2] += v2 * v2; ssq[3] += v3 * v3;
            u16 h0, l0, h1, l1, h2, l2, h3, l3;
            fsplit(v0, h0, l0); fsplit(v1, h1, l1);
            fsplit(v2, h2, l2); fsplit(v3, h3, l3);
            ushort4 hv = {h0, h1, h2, h3};
            ushort4 lv = {l0, l1, l2, l3};
            u16* yp = Y + (size_t)n * SY + chb;
            *(ushort4*)yp = hv;
            *(ushort4*)(yp + Cout) = lv;
        }
#pragma unroll
        for (int r = 0; r < 4; ++r) {
#pragma unroll
            for (int d = 1; d < 16; d <<= 1) {
                ssum[r] += __shfl_xor(ssum[r], d);
                ssq[r]  += __shfl_xor(ssq[r], d);
            }
        }
        if (l15 == 0) {
            const int chl = wm * 64 + i * 16 + q * 4;
#pragma unroll
            for (int r = 0; r < 4; ++r) {
                sstat[(wn * BM + chl + r) * 2]     = ssum[r];
                sstat[(wn * BM + chl + r) * 2 + 1] = ssq[r];
            }
        }
    }
    __syncthreads();
    if (tid < BM) {
        float s0 = 0.f, s1 = 0.f;
#pragma unroll
        for (int w = 0; w < CWv; ++w) {
            s0 += sstat[(w * BM + tid) * 2];
            s1 += sstat[(w * BM + tid) * 2 + 1];
        }
        atomicAdd(&stats[(m0 + tid) * 2], s0);
        atomicAdd(&stats[(m0 + tid) * 2 + 1], s1);
    }
}

// ---- BN finalize: stats(sum,sumsq) -> (scale, shift) -----------------------
__global__ void finalize_kernel(const float* __restrict__ stats, const float* __restrict__ g,
                                const float* __restrict__ be, float* __restrict__ bnp, int C) {
    const int c = blockIdx.x * blockDim.x + threadIdx.x;
    if (c >= C) return;
    const float inv = 1.0f / (float)Nn;
    const float mean = stats[c * 2] * inv;
    const float var = stats[c * 2 + 1] * inv - mean * mean;
    const float sc = g[c] / sqrtf(var + EPSf);
    bnp[c * 2] = sc;
    bnp[c * 2 + 1] = fmaf(-mean, sc, be[c]);
}

// ---- in-place BN+ReLU over [rows][2C], 8 logical elems/thread (uint4) ------
template<int C>
__global__ __launch_bounds__(256) void bnrelu_kernel(u16* x, const float* __restrict__ bnp) {
    const int t = blockIdx.x * 256 + threadIdx.x;
    const int i = t * 8;
    const int ch = i & (C - 1);
    const int row = i / C;
    u16* base = x + (size_t)row * (2 * C) + ch;
    const uint4 H = *(uint4*)base;
    const uint4 L = *(uint4*)(base + C);
    const unsigned hu[4] = {H.x, H.y, H.z, H.w};
    const unsigned lu[4] = {L.x, L.y, L.z, L.w};
    const float4 P0 = *(const float4*)(bnp + ch * 2);
    const float4 P1 = *(const float4*)(bnp + ch * 2 + 4);
    const float4 P2 = *(const float4*)(bnp + ch * 2 + 8);
    const float4 P3 = *(const float4*)(bnp + ch * 2 + 12);
    const float sc[8] = {P0.x, P0.z, P1.x, P1.z, P2.x, P2.z, P3.x, P3.z};
    const float sh[8] = {P0.y, P0.w, P1.y, P1.w, P2.y, P2.w, P3.y, P3.w};
    unsigned oh[4], ol[4];
#pragma unroll
    for (int e = 0; e < 4; ++e) {
        const int j = e * 2;
        const float a0 = fmaxf(fmaf(fjoin((u16)(hu[e] & 0xffff), (u16)(lu[e] & 0xffff)), sc[j], sh[j]), 0.f);
        const float a1 = fmaxf(fmaf(fjoin((u16)(hu[e] >> 16), (u16)(lu[e] >> 16)), sc[j + 1], sh[j + 1]), 0.f);
        u16 h0, l0, h1, l1;
        fsplit(a0, h0, l0); fsplit(a1, h1, l1);
        oh[e] = (unsigned)h0 | ((unsigned)h1 << 16);
        ol[e] = (unsigned)l0 | ((unsigned)l1 << 16);
    }
    *(uint4*)base = make_uint4(oh[0], oh[1], oh[2], oh[3]);
    *(uint4*)(base + C) = make_uint4(ol[0], ol[1], ol[2], ol[3]);
}

// ---- final 64->3 conv (BN+ReLU on split input), vectorized loads -----------
__global__ __launch_bounds__(256) void finalconv_pm(
    const u16* __restrict__ y3, const float* __restrict__ bnp,
    const float* __restrict__ wout, const float* __restrict__ bout,
    float* __restrict__ pts)
{
    __shared__ float swo[3][64];
    __shared__ float ssc[64], ssh[64];
    const int tid = threadIdx.x;
    if (tid < 192) swo[tid / 64][tid % 64] = wout[tid];
    if (tid < 64) { ssc[tid] = bnp[tid * 2]; ssh[tid] = bnp[tid * 2 + 1]; }
    __syncthreads();
    const int n = blockIdx.x * 256 + tid;
    const uint4* yph = (const uint4*)(y3 + (size_t)n * 128);
    float d0 = bout[0], d1 = bout[1], d2 = bout[2];
#pragma unroll
    for (int cc = 0; cc < 8; ++cc) {
        const uint4 H = yph[cc];
        const uint4 L = yph[8 + cc];
        const unsigned hu[4] = {H.x, H.y, H.z, H.w};
        const unsigned lu[4] = {L.x, L.y, L.z, L.w};
#pragma unroll
        for (int e = 0; e < 4; ++e) {
            const int c = cc * 8 + e * 2;
            const float v0 = fjoin((u16)(hu[e] & 0xffff), (u16)(lu[e] & 0xffff));
            const float v1 = fjoin((u16)(hu[e] >> 16), (u16)(lu[e] >> 16));
            const float a0 = fmaxf(fmaf(v0, ssc[c], ssh[c]), 0.f);
            const float a1 = fmaxf(fmaf(v1, ssc[c + 1], ssh[c + 1]), 0.f);
            d0 = fmaf(a0, swo[0][c], d0); d0 = fmaf(a1, swo[0][c + 1], d0);
            d1 = fmaf(a0, swo[1][c], d1); d1 = fmaf(a1, swo[1][c + 1], d1);
            d2 = fmaf(a0, swo[2][c], d2); d2 = fmaf(a1, swo[2][c + 1], d2);
        }
    }
    float4 p = {d0, d1, d2, d0 * d0 + d1 * d1 + d2 * d2};
    *(float4*)(pts + (size_t)n * 4) = p;
}

// ---- graph filtering: 8 threads/point in one wave, branchless insert -------
__global__ __launch_bounds__(512) void knn_kernel(const float* __restrict__ pts,
                                                  float* __restrict__ out) {
    __shared__ __align__(16) float4 sp[Mn];   // 32 KB -> 4 blocks/CU (wave cap)
    const int b = blockIdx.y;
    const int tid = threadIdx.x;
    const float4* pb = (const float4*)pts + (size_t)b * Mn;
    for (int i = tid; i < Mn; i += 512) sp[i] = pb[i];
    __syncthreads();
    const int lane = tid & 63;
    const int wv = tid >> 6;                    // 0..7
    const int seg = lane & 7;                   // segment 0..7
    const int ptl = (wv << 3) | (lane >> 3);    // point-local 0..63
    const int m = blockIdx.x * 64 + ptl;
    const float4 p = sp[m];
    float bd[8]; int bi[8];
#pragma unroll
    for (int k = 0; k < 8; ++k) { bd[k] = 1e30f; bi[k] = 0x7fffffff; }
    const int nb = seg << 8;
    for (int t = 0; t < 256; ++t) {
        const int n = nb | ((t + seg) & 255);   // stagger start by seg (bank tiling)
        const float4 q = sp[n];
        const float dot = fmaf(p.x, q.x, fmaf(p.y, q.y, p.z * q.z));
        float d = fmaf(-2.f, dot, q.w);         // key = dist - p.w (monotone)
        d = (n == m) ? 1e30f : d;               // exclude self
        const bool ins = d < bd[7];
        bd[7] = ins ? d : bd[7];
        bi[7] = ins ? n : bi[7];
        cswapd(bd[6], bi[6], bd[7], bi[7]);
        cswapd(bd[5], bi[5], bd[6], bi[6]);
        cswapd(bd[4], bi[4], bd[5], bi[5]);
        cswapd(bd[3], bi[3], bd[4], bi[4]);
        cswapd(bd[2], bi[2], bd[3], bi[3]);
        cswapd(bd[1], bi[1], bd[2], bi[2]);
        cswapd(bd[0], bi[0], bd[1], bi[1]);
    }
    // 3 shuffle merge rounds: partner = lane ^ r (same point, r in {1,2,4})
#pragma unroll
    for (int r = 1; r <= 4; r <<= 1) {
        float od[8]; int oi[8];
#pragma unroll
        for (int k = 0; k < 8; ++k) {
            od[k] = __shfl_xor(bd[k], r);
            oi[k] = __shfl_xor(bi[k], r);
        }
        float md[8]; int mi[8];
#pragma unroll
        for (int k = 0; k < 8; ++k) {           // lowest-8 of union (bitonic)
            const float da = bd[k], db = od[7 - k];
            const int   ia = bi[k], ib = oi[7 - k];
            const bool bl = (db < da) || (db == da && ib < ia);
            md[k] = bl ? db : da; mi[k] = bl ? ib : ia;
        }
#define CSM(a, c) cswap(md[a], mi[a], md[c], mi[c])
        CSM(0,4); CSM(1,5); CSM(2,6); CSM(3,7);
        CSM(0,2); CSM(1,3); CSM(4,6); CSM(5,7);
        CSM(0,1); CSM(2,3); CSM(4,5); CSM(6,7);
#undef CSM
#pragma unroll
        for (int k = 0; k < 8; ++k) { bd[k] = md[k]; bi[k] = mi[k]; }
    }
    if (seg == 0) {
        float nx = 0.f, ny = 0.f, nz = 0.f;
#pragma unroll
        for (int k = 0; k < 8; ++k) { const float4 q = sp[bi[k]]; nx += q.x; ny += q.y; nz += q.z; }
        const float s8 = 0.125f;
        float* ob = out + (size_t)b * 3 * Mn;
        ob[m]          = 2.f * p.x - nx * s8;
        ob[Mn + m]     = 2.f * p.y - ny * s8;
        ob[2 * Mn + m] = 2.f * p.z - nz * s8;
    }
}

// ============================================================================
extern "C" void kernel_launch(void* const* d_in, const int* in_sizes, int n_in,
                              void* d_out, int out_size, void* d_ws, size_t ws_size,
                              hipStream_t stream)
{
    (void)in_sizes; (void)n_in; (void)out_size;
    const float* z     = (const float*)d_in[0];
    const float* s     = (const float*)d_in[1];
    const float* w_m1  = (const float*)d_in[2];
    const float* b_m1  = (const float*)d_in[3];
    const float* w_m2  = (const float*)d_in[4];
    const float* b_m2  = (const float*)d_in[5];
    const float* w_out = (const float*)d_in[6];
    const float* b_out = (const float*)d_in[7];
    const float* w_c[4]  = {(const float*)d_in[8],  (const float*)d_in[12], (const float*)d_in[16], (const float*)d_in[20]};
    const float* b_c[4]  = {(const float*)d_in[9],  (const float*)d_in[13], (const float*)d_in[17], (const float*)d_in[21]};
    const float* g_c[4]  = {(const float*)d_in[10], (const float*)d_in[14], (const float*)d_in[18], (const float*)d_in[22]};
    const float* be_c[4] = {(const float*)d_in[11], (const float*)d_in[15], (const float*)d_in[19], (const float*)d_in[23]};

    char* ws = (char*)d_ws;
    const size_t MB = 1024ull * 1024ull;
    float* outp = (float*)d_out;
    if (ws_size < 256 * MB) return;   // proven: harness provides exactly 256 MiB

    // -------- overlay (full 256 MiB; stats/bnp in d_out, knn overwrites) ----
    // Phase A: xs @128..136, x1 @136..200, wbuf1 @200..201   | x2 @0..128
    // Phase B (after c0): y0 @128..256 (clobbers xs/x1/wbuf1, all dead)
    //   y1 @0..64 | y2 @64..96 | y3 @96..112 | pts @112..113 | wbuf2 @120..121
    //   all pairwise disjoint; every producer/consumer pair checked:
    //   c1: R{wbuf2,y0} W{y1}  c2: R{wbuf2,y1} W{y2}  c3: R{wbuf2,y2} W{y3}
    //   fc: R{y3} W{pts}       knn: R{pts} W{d_out}
    u16*   wbuf1 = (u16*)(ws + 200 * MB);     // m1+m2 split weights (544 KiB)
    u16*   wbuf2 = (u16*)(ws + 120 * MB);     // c1/c2/c3 split weights (672 KiB)
    float* stats = (float*)d_out;             // 16 KiB (knn overwrites last)
    float* bnp   = (float*)d_out + 4096;      // 16 KiB
    u16*   xs  = (u16*)(ws + 128 * MB);
    u16*   x1  = (u16*)(ws + 136 * MB);
    u16*   x2  = (u16*)ws;
    u16*   y0  = (u16*)(ws + 128 * MB);
    u16*   y1  = (u16*)ws;
    u16*   y2  = (u16*)(ws + 64 * MB);
    u16*   y3  = (u16*)(ws + 96 * MB);
    float* pts = (float*)(ws + 112 * MB);

    prep_kernel<<<801, 256, 0, stream>>>(w_m1, w_m2, s, wbuf1, xs, stats);
    // m1: [N][32] -> [N][256]  (Ntiles=512, MY=2 -> 1024 blocks)
    mfma_gemm<2, 2, 0, 2><<<1024, 256, 0, stream>>>(wbuf1, xs, x1, b_m1, nullptr, nullptr, 256, 32);
    // m2: [N][256] -> [N][512] (Ntiles=512, MY=4 -> 2048 blocks)
    mfma_gemm<2, 2, 1, 4><<<2048, 256, 0, stream>>>(wbuf1 + 16384, x1, x2, b_m2, z, nullptr, 512, 256);
    // c0: [N][512] -> [N][512] SINGLE launch (Ntiles=512, MY=4 -> 2048 blocks);
    //     A from fp32 w_c0 with in-kernel split; x2 and y0 fully disjoint.
    mfma_gemm_wf<2, 2, 4><<<2048, 256, 0, stream>>>(w_c[0], x2, y0, b_c[0], stats + 0, 512, 512);
    wcvt2_kernel<<<672, 256, 0, stream>>>(w_c[1], w_c[2], w_c[3], wbuf2);
    finalize_kernel<<<2, 256, 0, stream>>>(stats + 0, g_c[0], be_c[0], bnp + 0, 512);
    bnrelu_kernel<512><<<16384, 256, 0, stream>>>(y0, bnp + 0);
    // c1: [N][512] -> [N][256] (Ntiles=512, MY=2 -> 1024 blocks)
    mfma_gemm<2, 2, 2, 2><<<1024, 256, 0, stream>>>(wbuf2, y0, y1, b_c[1], nullptr, stats + 1024, 256, 512);
    finalize_kernel<<<1, 256, 0, stream>>>(stats + 1024, g_c[1], be_c[1], bnp + 1024, 256);
    bnrelu_kernel<256><<<8192, 256, 0, stream>>>(y1, bnp + 1024);
    // c2: [N][256] -> [N][128] (Ntiles=512, MY=1 -> 512 blocks)
    mfma_gemm<2, 2, 2, 1><<<512, 256, 0, stream>>>(wbuf2 + 262144, y1, y2, b_c[2], nullptr, stats + 2048, 128, 256);
    finalize_kernel<<<1, 128, 0, stream>>>(stats + 2048, g_c[2], be_c[2], bnp + 2048, 128);
    bnrelu_kernel<128><<<4096, 256, 0, stream>>>(y2, bnp + 2048);
    // c3: [N][128] -> [N][64]  (BM=64, BN=256; Ntiles=256, MY=1 -> 256 blocks)
    mfma_gemm<1, 4, 2, 1><<<256, 256, 0, stream>>>(wbuf2 + 327680, y2, y3, b_c[3], nullptr, stats + 3072, 64, 128);
    finalize_kernel<<<1, 64, 0, stream>>>(stats + 3072, g_c[3], be_c[3], bnp + 3072, 64);
    finalconv_pm<<<Nn / 256, 256, 0, stream>>>(y3, bnp + 3072, w_out, b_out, pts);
    knn_kernel<<<dim3(Mn / 64, Bn), 512, 0, stream>>>(pts, outp);
}

// Round 17
// 953.002 us; speedup vs baseline: 1.0353x; 1.0353x over previous
//
#include <hip/hip_runtime.h>
#include <math.h>

#define Bn 32
#define Mn 2048
#define Nn 65536      // Bn * Mn
#define Hn 32768      // Nn / 2 (chunk for race-free c0)
#define SDn 16
#define CWn 512
#define EPSf 1e-5f
#define KGF 8
#define WTOT 573440   // logical weight elements
#define LSC 2048.0f   // lo-plane scale (2^11)
#define LSCI (1.0f / 2048.0f)

typedef unsigned short u16;
typedef _Float16 fp16_t;
typedef __attribute__((ext_vector_type(8))) _Float16 h8v;  // MFMA A/B frag: 8 f16
typedef __attribute__((ext_vector_type(4))) float f4v;     // MFMA C/D frag: 4 fp32

__device__ __forceinline__ u16 f2h(float f) {
    union { fp16_t h; u16 u; } c; c.h = (fp16_t)f; return c.u;
}
__device__ __forceinline__ float h2f(u16 u) {
    union { fp16_t h; u16 u; } c; c.u = u; return (float)c.h;
}
__device__ __forceinline__ void fsplit(float f, u16& hi, u16& lo) {
    hi = f2h(f);
    lo = f2h((f - h2f(hi)) * LSC);
}
__device__ __forceinline__ float fjoin(u16 hi, u16 lo) {
    return h2f(hi) + h2f(lo) * LSCI;
}
// async global->LDS, 16 bytes/lane (dest must be wave-uniform base + lane*16)
__device__ __forceinline__ void gll16(const u16* g, u16* l) {
    __builtin_amdgcn_global_load_lds((const __attribute__((address_space(1))) void*)g,
                                     (__attribute__((address_space(3))) void*)l, 16, 0, 0);
}
// lexicographic comparator swap (merge tail): keep (d0,i0) <= (d1,i1)
__device__ __forceinline__ void cswap(float& d0, int& i0, float& d1, int& i1) {
    const bool gt = (d0 > d1) || (d0 == d1 && i0 > i1);
    const float ta = gt ? d1 : d0, tb = gt ? d0 : d1;
    const int   ua = gt ? i1 : i0, ub = gt ? i0 : i1;
    d0 = ta; d1 = tb; i0 = ua; i1 = ub;
}
// distance-only stable comparator swap (hot loop): swap iff d0 > d1 strictly
__device__ __forceinline__ void cswapd(float& d0, int& i0, float& d1, int& i1) {
    const bool gt = d0 > d1;
    const float ta = gt ? d1 : d0, tb = gt ? d0 : d1;
    const int   ua = gt ? i1 : i0, ub = gt ? i0 : i1;
    d0 = ta; d1 = tb; i0 = ua; i1 = ub;
}

// ============================================================================
// prep: weights fp32 -> split layout, normalize s -> xs, zero stats (fused)
// ============================================================================
__global__ __launch_bounds__(256) void prep_kernel(
    const float* __restrict__ wm1, const float* __restrict__ wm2,
    const float* __restrict__ wc0, const float* __restrict__ wc1,
    const float* __restrict__ wc2, const float* __restrict__ wc3,
    const float* __restrict__ s,
    u16* __restrict__ wbuf, u16* __restrict__ xs, float* __restrict__ stats)
{
    const int bid = blockIdx.x;
    const int tid = threadIdx.x;
    if (bid < 2240) {
        // ---- weight conversion: [Cout][hi[Cin] | lo[Cin]] ----
        int i = bid * 256 + tid;
        float w; int r, k, Cin; size_t base;
        if (i < 8192) {                              // m1 padded [256][32]
            r = i >> 5; k = i & 31; Cin = 32; base = 0;
            w = (k < SDn) ? wm1[r * SDn + k] : 0.f;
        } else {
            int j = i - 8192;
            if (j < 131072)                    { r = j >> 8; k = j & 255; Cin = 256; base = 16384;   w = wm2[j]; }
            else if ((j -= 131072) < 262144)   { r = j >> 9; k = j & 511; Cin = 512; base = 278528;  w = wc0[j]; }
            else if ((j -= 262144) < 131072)   { r = j >> 9; k = j & 511; Cin = 512; base = 802816;  w = wc1[j]; }
            else if ((j -= 131072) < 32768)    { r = j >> 8; k = j & 255; Cin = 256; base = 1064960; w = wc2[j]; }
            else { j -= 32768;                   r = j >> 7; k = j & 127; Cin = 128; base = 1130496; w = wc3[j]; }
        }
        const size_t addr = base + (size_t)r * (2 * Cin) + k;
        u16 hi, lo; fsplit(w, hi, lo);
        wbuf[addr] = hi;
        wbuf[addr + Cin] = lo;
    } else if (bid < 2496) {
        // ---- normalize s[B,16,M] -> xs[N][64] (hi[32]|lo[32], upper 16 zero)
        const int b2 = bid - 2240;
        const int m = (b2 & 7) * 256 + tid;
        const int b = b2 >> 3;
        const float* sp = s + (size_t)b * SDn * Mn + m;
        float v[SDn]; float sq = 0.f;
#pragma unroll
        for (int c = 0; c < SDn; ++c) { v[c] = sp[(size_t)c * Mn]; sq += v[c] * v[c]; }
        const float r = 1.0f / sqrtf(sq);
        unsigned int uh[8], ul[8];
#pragma unroll
        for (int c = 0; c < 8; ++c) {
            u16 h0, l0, h1, l1;
            fsplit(v[2 * c] * r, h0, l0);
            fsplit(v[2 * c + 1] * r, h1, l1);
            uh[c] = (unsigned int)h0 | ((unsigned int)h1 << 16);
            ul[c] = (unsigned int)l0 | ((unsigned int)l1 << 16);
        }
        uint4* xp = (uint4*)(xs + (size_t)(b * Mn + m) * 64);
        xp[0] = make_uint4(uh[0], uh[1], uh[2], uh[3]);
        xp[1] = make_uint4(uh[4], uh[5], uh[6], uh[7]);
        xp[2] = make_uint4(0, 0, 0, 0);
        xp[3] = make_uint4(0, 0, 0, 0);
        xp[4] = make_uint4(ul[0], ul[1], ul[2], ul[3]);
        xp[5] = make_uint4(ul[4], ul[5], ul[6], ul[7]);
        xp[6] = make_uint4(0, 0, 0, 0);
        xp[7] = make_uint4(0, 0, 0, 0);
    } else {
        // ---- zero BN stats (4096 floats) ----
        float4 z4 = {0.f, 0.f, 0.f, 0.f};
        float4* sp4 = (float4*)stats;
#pragma unroll
        for (int k = 0; k < 4; ++k) sp4[tid * 4 + k] = z4;
    }
}

// ---- split fp16 MFMA GEMM, async staging, XCD remap, swizzled LDS ----------
// acc0 = Wh*Xh ; accL = Wh*Xl' + Wl'*Xh ; result = acc0 + accL/2048
template<int RW, int CWv, int EPI, int MY>
__global__ __launch_bounds__(256) void mfma_gemm(
    const u16* __restrict__ W, const u16* __restrict__ X, u16* __restrict__ Y,
    const float* __restrict__ bias, const float* __restrict__ zmod,
    float* __restrict__ stats, int Cout, int Cin)
{
    constexpr int BM = RW * 64, BN = CWv * 64;
    constexpr int ASEG = BM / 64, BSEG = BN / 64;
    constexpr int LMY = (MY == 1) ? 0 : (MY == 2) ? 1 : (MY == 4) ? 2 : 3;
    __shared__ __align__(16) u16 Ah[BM * 32], Al[BM * 32];
    __shared__ __align__(16) u16 Bh[BN * 32], Bl[BN * 32];
    __shared__ float sstat[(EPI == 2) ? (CWv * BM * 2) : 1];

    const int tid = threadIdx.x;
    const int wave = tid >> 6;
    const int lane = tid & 63;
    const int wm = wave & (RW - 1), wn = wave / RW;
    const int l15 = lane & 15, q = lane >> 4;
    const int lin = blockIdx.x;
    const int xcd = lin & 7;
    const int jj = lin >> 3;
    const int m0 = (jj & (MY - 1)) * BM;
    const int n0 = (xcd + ((jj >> LMY) << 3)) * BN;
    const int SW = 2 * Cin;

    f4v acc0[4][4], accL[4][4];
#pragma unroll
    for (int i = 0; i < 4; ++i)
#pragma unroll
        for (int j = 0; j < 4; ++j) {
            acc0[i][j] = (f4v){0.f, 0.f, 0.f, 0.f};
            accL[i][j] = (f4v){0.f, 0.f, 0.f, 0.f};
        }

    const int nsteps = Cin >> 5;
    for (int ks = 0; ks < nsteps; ++ks) {
        const int k0 = ks << 5;
        __syncthreads();   // previous iteration's frag reads done before overwrite
#pragma unroll
        for (int s = 0; s < ASEG; ++s) {
            const int flat = s * 256 + tid;
            const int row = flat >> 2;
            const int qs = (flat & 3) ^ ((row >> 1) & 3);   // swizzled source chunk
            const u16* ga = W + (size_t)(m0 + row) * SW + k0 + qs * 8;
            gll16(ga, Ah + flat * 8);
            gll16(ga + Cin, Al + flat * 8);
        }
#pragma unroll
        for (int s = 0; s < BSEG; ++s) {
            const int flat = s * 256 + tid;
            const int row = flat >> 2;
            const int qs = (flat & 3) ^ ((row >> 1) & 3);
            const u16* gb = X + (size_t)(n0 + row) * SW + k0 + qs * 8;
            gll16(gb, Bh + flat * 8);
            gll16(gb + Cin, Bl + flat * 8);
        }
        __syncthreads();   // drains vmcnt -> LDS tiles ready
        h8v afh[4], afl[4], bfh[4], bfl[4];
#pragma unroll
        for (int i = 0; i < 4; ++i) {
            const int ar = wm * 64 + i * 16 + l15;
            const int ao = ar * 32 + ((q ^ ((ar >> 1) & 3)) << 3);
            afh[i] = *(const h8v*)(Ah + ao);
            afl[i] = *(const h8v*)(Al + ao);
        }
#pragma unroll
        for (int j = 0; j < 4; ++j) {
            const int br = wn * 64 + j * 16 + l15;
            const int bo = br * 32 + ((q ^ ((br >> 1) & 3)) << 3);
            bfh[j] = *(const h8v*)(Bh + bo);
            bfl[j] = *(const h8v*)(Bl + bo);
        }
#pragma unroll
        for (int i = 0; i < 4; ++i)
#pragma unroll
            for (int j = 0; j < 4; ++j) {
                accL[i][j] = __builtin_amdgcn_mfma_f32_16x16x32_f16(afh[i], bfl[j], accL[i][j], 0, 0, 0);
                accL[i][j] = __builtin_amdgcn_mfma_f32_16x16x32_f16(afl[i], bfh[j], accL[i][j], 0, 0, 0);
                acc0[i][j] = __builtin_amdgcn_mfma_f32_16x16x32_f16(afh[i], bfh[j], acc0[i][j], 0, 0, 0);
            }
    }

    // ---- epilogue ----
    const int bb = n0 >> 11;
    const int SY = 2 * Cout;
#pragma unroll
    for (int i = 0; i < 4; ++i) {
        const int chb = m0 + wm * 64 + i * 16 + q * 4;
        const float4 bias4 = *(const float4*)(bias + chb);
        float z0 = 0.f, z1 = 0.f, z2 = 0.f, z3 = 0.f;
        if constexpr (EPI == 1) {
            const float4 z4 = *(const float4*)(zmod + bb * CWn + chb);
            z0 = z4.x; z1 = z4.y; z2 = z4.z; z3 = z4.w;
        }
        float ssum[4] = {0.f, 0.f, 0.f, 0.f}, ssq[4] = {0.f, 0.f, 0.f, 0.f};
#pragma unroll
        for (int j = 0; j < 4; ++j) {
            const int n = n0 + wn * 64 + j * 16 + l15;
            float v0 = fmaf(accL[i][j][0], LSCI, acc0[i][j][0]) + bias4.x;
            float v1 = fmaf(accL[i][j][1], LSCI, acc0[i][j][1]) + bias4.y;
            float v2 = fmaf(accL[i][j][2], LSCI, acc0[i][j][2]) + bias4.z;
            float v3 = fmaf(accL[i][j][3], LSCI, acc0[i][j][3]) + bias4.w;
            if constexpr (EPI == 0) {
                v0 = fmaxf(v0, 0.f); v1 = fmaxf(v1, 0.f); v2 = fmaxf(v2, 0.f); v3 = fmaxf(v3, 0.f);
            } else if constexpr (EPI == 1) {
                v0 = fminf(fmaxf(v0, -1.f), 1.f) * z0;
                v1 = fminf(fmaxf(v1, -1.f), 1.f) * z1;
                v2 = fminf(fmaxf(v2, -1.f), 1.f) * z2;
                v3 = fminf(fmaxf(v3, -1.f), 1.f) * z3;
            } else {
                ssum[0] += v0; ssum[1] += v1; ssum[2] += v2; ssum[3] += v3;
                ssq[0] += v0 * v0; ssq[1] += v1 * v1; ssq[2] += v2 * v2; ssq[3] += v3 * v3;
            }
            u16 h0, l0, h1, l1, h2, l2, h3, l3;
            fsplit(v0, h0, l0); fsplit(v1, h1, l1);
            fsplit(v2, h2, l2); fsplit(v3, h3, l3);
            ushort4 hv = {h0, h1, h2, h3};
            ushort4 lv = {l0, l1, l2, l3};
            u16* yp = Y + (size_t)n * SY + chb;
            *(ushort4*)yp = hv;
            *(ushort4*)(yp + Cout) = lv;
        }
        if constexpr (EPI == 2) {
#pragma unroll
            for (int r = 0; r < 4; ++r) {
#pragma unroll
                for (int d = 1; d < 16; d <<= 1) {
                    ssum[r] += __shfl_xor(ssum[r], d);
                    ssq[r]  += __shfl_xor(ssq[r], d);
                }
            }
            if (l15 == 0) {
                const int chl = wm * 64 + i * 16 + q * 4;
#pragma unroll
                for (int r = 0; r < 4; ++r) {
                    sstat[(wn * BM + chl + r) * 2]     = ssum[r];
                    sstat[(wn * BM + chl + r) * 2 + 1] = ssq[r];
                }
            }
        }
    }
    if constexpr (EPI == 2) {
        __syncthreads();
        if (tid < BM) {
            float s0 = 0.f, s1 = 0.f;
#pragma unroll
            for (int w = 0; w < CWv; ++w) {
                s0 += sstat[(w * BM + tid) * 2];
                s1 += sstat[(w * BM + tid) * 2 + 1];
            }
            atomicAdd(&stats[(m0 + tid) * 2], s0);
            atomicAdd(&stats[(m0 + tid) * 2 + 1], s1);
        }
    }
}

// ---- BN finalize: stats(sum,sumsq) -> (scale, shift) -----------------------
__global__ void finalize_kernel(const float* __restrict__ stats, const float* __restrict__ g,
                                const float* __restrict__ be, float* __restrict__ bnp, int C) {
    const int c = blockIdx.x * blockDim.x + threadIdx.x;
    if (c >= C) return;
    const float inv = 1.0f / (float)Nn;
    const float mean = stats[c * 2] * inv;
    const float var = stats[c * 2 + 1] * inv - mean * mean;
    const float sc = g[c] / sqrtf(var + EPSf);
    bnp[c * 2] = sc;
    bnp[c * 2 + 1] = fmaf(-mean, sc, be[c]);
}

// ---- in-place BN+ReLU over [rows][2C], 8 logical elems/thread (uint4) ------
template<int C>
__global__ __launch_bounds__(256) void bnrelu_kernel(u16* x, const float* __restrict__ bnp) {
    const int t = blockIdx.x * 256 + threadIdx.x;
    const int i = t * 8;
    const int ch = i & (C - 1);
    const int row = i / C;
    u16* base = x + (size_t)row * (2 * C) + ch;
    const uint4 H = *(uint4*)base;
    const uint4 L = *(uint4*)(base + C);
    const unsigned hu[4] = {H.x, H.y, H.z, H.w};
    const unsigned lu[4] = {L.x, L.y, L.z, L.w};
    const float4 P0 = *(const float4*)(bnp + ch * 2);
    const float4 P1 = *(const float4*)(bnp + ch * 2 + 4);
    const float4 P2 = *(const float4*)(bnp + ch * 2 + 8);
    const float4 P3 = *(const float4*)(bnp + ch * 2 + 12);
    const float sc[8] = {P0.x, P0.z, P1.x, P1.z, P2.x, P2.z, P3.x, P3.z};
    const float sh[8] = {P0.y, P0.w, P1.y, P1.w, P2.y, P2.w, P3.y, P3.w};
    unsigned oh[4], ol[4];
#pragma unroll
    for (int e = 0; e < 4; ++e) {
        const int j = e * 2;
        const float a0 = fmaxf(fmaf(fjoin((u16)(hu[e] & 0xffff), (u16)(lu[e] & 0xffff)), sc[j], sh[j]), 0.f);
        const float a1 = fmaxf(fmaf(fjoin((u16)(hu[e] >> 16), (u16)(lu[e] >> 16)), sc[j + 1], sh[j + 1]), 0.f);
        u16 h0, l0, h1, l1;
        fsplit(a0, h0, l0); fsplit(a1, h1, l1);
        oh[e] = (unsigned)h0 | ((unsigned)h1 << 16);
        ol[e] = (unsigned)l0 | ((unsigned)l1 << 16);
    }
    *(uint4*)base = make_uint4(oh[0], oh[1], oh[2], oh[3]);
    *(uint4*)(base + C) = make_uint4(ol[0], ol[1], ol[2], ol[3]);
}

// ---- final 64->3 conv (BN+ReLU on split input), vectorized loads -----------
__global__ __launch_bounds__(256) void finalconv_pm(
    const u16* __restrict__ y3, const float* __restrict__ bnp,
    const float* __restrict__ wout, const float* __restrict__ bout,
    float* __restrict__ pts)
{
    __shared__ float swo[3][64];
    __shared__ float ssc[64], ssh[64];
    const int tid = threadIdx.x;
    if (tid < 192) swo[tid / 64][tid % 64] = wout[tid];
    if (tid < 64) { ssc[tid] = bnp[tid * 2]; ssh[tid] = bnp[tid * 2 + 1]; }
    __syncthreads();
    const int n = blockIdx.x * 256 + tid;
    const uint4* yph = (const uint4*)(y3 + (size_t)n * 128);
    float d0 = bout[0], d1 = bout[1], d2 = bout[2];
#pragma unroll
    for (int cc = 0; cc < 8; ++cc) {
        const uint4 H = yph[cc];
        const uint4 L = yph[8 + cc];
        const unsigned hu[4] = {H.x, H.y, H.z, H.w};
        const unsigned lu[4] = {L.x, L.y, L.z, L.w};
#pragma unroll
        for (int e = 0; e < 4; ++e) {
            const int c = cc * 8 + e * 2;
            const float v0 = fjoin((u16)(hu[e] & 0xffff), (u16)(lu[e] & 0xffff));
            const float v1 = fjoin((u16)(hu[e] >> 16), (u16)(lu[e] >> 16));
            const float a0 = fmaxf(fmaf(v0, ssc[c], ssh[c]), 0.f);
            const float a1 = fmaxf(fmaf(v1, ssc[c + 1], ssh[c + 1]), 0.f);
            d0 = fmaf(a0, swo[0][c], d0); d0 = fmaf(a1, swo[0][c + 1], d0);
            d1 = fmaf(a0, swo[1][c], d1); d1 = fmaf(a1, swo[1][c + 1], d1);
            d2 = fmaf(a0, swo[2][c], d2); d2 = fmaf(a1, swo[2][c + 1], d2);
        }
    }
    float4 p = {d0, d1, d2, d0 * d0 + d1 * d1 + d2 * d2};
    *(float4*)(pts + (size_t)n * 4) = p;
}

// ---- graph filtering: 8 threads/point in one wave, branchless insert -------
// Key d' = q.w - 2*dot: monotone shift of true distance by the per-point
// constant p.w -> identical selection (d never output). Unguarded bubble
// (r13 __any guard measured slower: exec-mask churn > saved VALU).
__global__ __launch_bounds__(512) void knn_kernel(const float* __restrict__ pts,
                                                  float* __restrict__ out) {
    __shared__ __align__(16) float4 sp[Mn];   // 32 KB -> 4 blocks/CU (wave cap)
    const int b = blockIdx.y;
    const int tid = threadIdx.x;
    const float4* pb = (const float4*)pts + (size_t)b * Mn;
    for (int i = tid; i < Mn; i += 512) sp[i] = pb[i];
    __syncthreads();
    const int lane = tid & 63;
    const int wv = tid >> 6;                    // 0..7
    const int seg = lane & 7;                   // segment 0..7
    const int ptl = (wv << 3) | (lane >> 3);    // point-local 0..63
    const int m = blockIdx.x * 64 + ptl;
    const float4 p = sp[m];
    float bd[8]; int bi[8];
#pragma unroll
    for (int k = 0; k < 8; ++k) { bd[k] = 1e30f; bi[k] = 0x7fffffff; }
    const int nb = seg << 8;
    for (int t = 0; t < 256; ++t) {
        const int n = nb | ((t + seg) & 255);   // stagger start by seg (bank tiling)
        const float4 q = sp[n];
        const float dot = fmaf(p.x, q.x, fmaf(p.y, q.y, p.z * q.z));
        float d = fmaf(-2.f, dot, q.w);         // key = dist - p.w (monotone)
        d = (n == m) ? 1e30f : d;               // exclude self
        const bool ins = d < bd[7];
        bd[7] = ins ? d : bd[7];
        bi[7] = ins ? n : bi[7];
        cswapd(bd[6], bi[6], bd[7], bi[7]);
        cswapd(bd[5], bi[5], bd[6], bi[6]);
        cswapd(bd[4], bi[4], bd[5], bi[5]);
        cswapd(bd[3], bi[3], bd[4], bi[4]);
        cswapd(bd[2], bi[2], bd[3], bi[3]);
        cswapd(bd[1], bi[1], bd[2], bi[2]);
        cswapd(bd[0], bi[0], bd[1], bi[1]);
    }
    // 3 shuffle merge rounds: partner = lane ^ r (same point, r in {1,2,4})
#pragma unroll
    for (int r = 1; r <= 4; r <<= 1) {
        float od[8]; int oi[8];
#pragma unroll
        for (int k = 0; k < 8; ++k) {
            od[k] = __shfl_xor(bd[k], r);
            oi[k] = __shfl_xor(bi[k], r);
        }
        float md[8]; int mi[8];
#pragma unroll
        for (int k = 0; k < 8; ++k) {           // lowest-8 of union (bitonic)
            const float da = bd[k], db = od[7 - k];
            const int   ia = bi[k], ib = oi[7 - k];
            const bool bl = (db < da) || (db == da && ib < ia);
            md[k] = bl ? db : da; mi[k] = bl ? ib : ia;
        }
#define CSM(a, c) cswap(md[a], mi[a], md[c], mi[c])
        CSM(0,4); CSM(1,5); CSM(2,6); CSM(3,7);
        CSM(0,2); CSM(1,3); CSM(4,6); CSM(5,7);
        CSM(0,1); CSM(2,3); CSM(4,5); CSM(6,7);
#undef CSM
#pragma unroll
        for (int k = 0; k < 8; ++k) { bd[k] = md[k]; bi[k] = mi[k]; }
    }
    if (seg == 0) {
        float nx = 0.f, ny = 0.f, nz = 0.f;
#pragma unroll
        for (int k = 0; k < 8; ++k) { const float4 q = sp[bi[k]]; nx += q.x; ny += q.y; nz += q.z; }
        const float s8 = 0.125f;
        float* ob = out + (size_t)b * 3 * Mn;
        ob[m]          = 2.f * p.x - nx * s8;
        ob[Mn + m]     = 2.f * p.y - ny * s8;
        ob[2 * Mn + m] = 2.f * p.z - nz * s8;
    }
}

// ============================================================================
extern "C" void kernel_launch(void* const* d_in, const int* in_sizes, int n_in,
                              void* d_out, int out_size, void* d_ws, size_t ws_size,
                              hipStream_t stream)
{
    (void)in_sizes; (void)n_in; (void)out_size;
    const float* z     = (const float*)d_in[0];
    const float* s     = (const float*)d_in[1];
    const float* w_m1  = (const float*)d_in[2];
    const float* b_m1  = (const float*)d_in[3];
    const float* w_m2  = (const float*)d_in[4];
    const float* b_m2  = (const float*)d_in[5];
    const float* w_out = (const float*)d_in[6];
    const float* b_out = (const float*)d_in[7];
    const float* w_c[4]  = {(const float*)d_in[8],  (const float*)d_in[12], (const float*)d_in[16], (const float*)d_in[20]};
    const float* b_c[4]  = {(const float*)d_in[9],  (const float*)d_in[13], (const float*)d_in[17], (const float*)d_in[21]};
    const float* g_c[4]  = {(const float*)d_in[10], (const float*)d_in[14], (const float*)d_in[18], (const float*)d_in[22]};
    const float* be_c[4] = {(const float*)d_in[11], (const float*)d_in[15], (const float*)d_in[19], (const float*)d_in[23]};

    char* ws = (char*)d_ws;
    const size_t MB = 1024ull * 1024ull;
    float* outp = (float*)d_out;
    if (ws_size < 208 * MB) return;   // proven: harness provides >= 208 MiB

    // -------- split-fp16 MFMA path (peak 204 MiB) --------
    u16*   wbuf  = (u16*)ws;
    float* stats = (float*)(ws + 3 * MB);
    float* bnp   = stats + 4096;
    u16*   xs  = (u16*)(ws + 4 * MB);
    u16*   x1  = (u16*)(ws + 12 * MB);
    u16*   x2  = (u16*)(ws + 76 * MB);
    u16*   y0  = (u16*)(ws + 12 * MB);   // contiguous after both chunks
    u16*   y0a = (u16*)(ws + 12 * MB);   // rows [0, 32K)
    u16*   y0b = (u16*)(ws + 76 * MB);   // rows [32K, 64K)
    u16*   y1  = (u16*)(ws + 140 * MB);
    u16*   y2  = (u16*)(ws + 12 * MB);
    u16*   y3  = (u16*)(ws + 76 * MB);
    float* pts = (float*)(ws + 4 * MB);

    prep_kernel<<<2497, 256, 0, stream>>>(w_m1, w_m2, w_c[0], w_c[1], w_c[2], w_c[3], s, wbuf, xs, stats);
    // m1: [N][32] -> [N][256]  (Ntiles=512, MY=2 -> 1024 blocks)
    mfma_gemm<2, 2, 0, 2><<<1024, 256, 0, stream>>>(wbuf, xs, x1, b_m1, nullptr, nullptr, 256, 32);
    // m2: [N][256] -> [N][512] (Ntiles=512, MY=4 -> 2048 blocks)
    mfma_gemm<2, 2, 1, 4><<<2048, 256, 0, stream>>>(wbuf + 16384, x1, x2, b_m2, z, nullptr, 512, 256);
    // c0 a/b: rows halves      (Ntiles=256, MY=4 -> 1024 blocks each)
    mfma_gemm<2, 2, 2, 4><<<1024, 256, 0, stream>>>(wbuf + 278528, x2, y0a, b_c[0], nullptr, stats + 0, 512, 512);
    mfma_gemm<2, 2, 2, 4><<<1024, 256, 0, stream>>>(wbuf + 278528, x2 + (size_t)Hn * 1024, y0b, b_c[0], nullptr, stats + 0, 512, 512);
    finalize_kernel<<<2, 256, 0, stream>>>(stats + 0, g_c[0], be_c[0], bnp + 0, 512);
    bnrelu_kernel<512><<<16384, 256, 0, stream>>>(y0, bnp + 0);
    // c1: [N][512] -> [N][256] (Ntiles=512, MY=2 -> 1024 blocks)
    mfma_gemm<2, 2, 2, 2><<<1024, 256, 0, stream>>>(wbuf + 802816, y0, y1, b_c[1], nullptr, stats + 1024, 256, 512);
    finalize_kernel<<<1, 256, 0, stream>>>(stats + 1024, g_c[1], be_c[1], bnp + 1024, 256);
    bnrelu_kernel<256><<<8192, 256, 0, stream>>>(y1, bnp + 1024);
    // c2: [N][256] -> [N][128] (Ntiles=512, MY=1 -> 512 blocks)
    mfma_gemm<2, 2, 2, 1><<<512, 256, 0, stream>>>(wbuf + 1064960, y1, y2, b_c[2], nullptr, stats + 2048, 128, 256);
    finalize_kernel<<<1, 128, 0, stream>>>(stats + 2048, g_c[2], be_c[2], bnp + 2048, 128);
    bnrelu_kernel<128><<<4096, 256, 0, stream>>>(y2, bnp + 2048);
    // c3: [N][128] -> [N][64]  (BM=64, BN=256; Ntiles=256, MY=1 -> 256 blocks)
    mfma_gemm<1, 4, 2, 1><<<256, 256, 0, stream>>>(wbuf + 1130496, y2, y3, b_c[3], nullptr, stats + 3072, 64, 128);
    finalize_kernel<<<1, 64, 0, stream>>>(stats + 3072, g_c[3], be_c[3], bnp + 3072, 64);
    finalconv_pm<<<Nn / 256, 256, 0, stream>>>(y3, bnp + 3072, w_out, b_out, pts);
    knn_kernel<<<dim3(Mn / 64, Bn), 512, 0, stream>>>(pts, outp);
}

// Round 18
// 929.515 us; speedup vs baseline: 1.0615x; 1.0253x over previous
//
#include <hip/hip_runtime.h>
#include <math.h>

#define Bn 32
#define Mn 2048
#define Nn 65536      // Bn * Mn
#define Hn 32768      // Nn / 2 (chunk for race-free c0)
#define SDn 16
#define CWn 512
#define EPSf 1e-5f
#define KGF 8
#define WTOT 573440   // logical weight elements
#define LSC 2048.0f   // lo-plane scale (2^11)
#define LSCI (1.0f / 2048.0f)

typedef unsigned short u16;
typedef _Float16 fp16_t;
typedef __attribute__((ext_vector_type(8))) _Float16 h8v;  // MFMA A/B frag: 8 f16
typedef __attribute__((ext_vector_type(4))) float f4v;     // MFMA C/D frag: 4 fp32

__device__ __forceinline__ u16 f2h(float f) {
    union { fp16_t h; u16 u; } c; c.h = (fp16_t)f; return c.u;
}
__device__ __forceinline__ float h2f(u16 u) {
    union { fp16_t h; u16 u; } c; c.u = u; return (float)c.h;
}
__device__ __forceinline__ void fsplit(float f, u16& hi, u16& lo) {
    hi = f2h(f);
    lo = f2h((f - h2f(hi)) * LSC);
}
__device__ __forceinline__ float fjoin(u16 hi, u16 lo) {
    return h2f(hi) + h2f(lo) * LSCI;
}
// async global->LDS, 16 bytes/lane (dest must be wave-uniform base + lane*16)
__device__ __forceinline__ void gll16(const u16* g, u16* l) {
    __builtin_amdgcn_global_load_lds((const __attribute__((address_space(1))) void*)g,
                                     (__attribute__((address_space(3))) void*)l, 16, 0, 0);
}
// lexicographic comparator swap (merge tail): keep (d0,i0) <= (d1,i1)
__device__ __forceinline__ void cswap(float& d0, int& i0, float& d1, int& i1) {
    const bool gt = (d0 > d1) || (d0 == d1 && i0 > i1);
    const float ta = gt ? d1 : d0, tb = gt ? d0 : d1;
    const int   ua = gt ? i1 : i0, ub = gt ? i0 : i1;
    d0 = ta; d1 = tb; i0 = ua; i1 = ub;
}
// distance-only stable comparator swap (hot loop): swap iff d0 > d1 strictly
__device__ __forceinline__ void cswapd(float& d0, int& i0, float& d1, int& i1) {
    const bool gt = d0 > d1;
    const float ta = gt ? d1 : d0, tb = gt ? d0 : d1;
    const int   ua = gt ? i1 : i0, ub = gt ? i0 : i1;
    d0 = ta; d1 = tb; i0 = ua; i1 = ub;
}

// ============================================================================
// prep: weights fp32 -> split layout, normalize s -> xs, zero stats (fused)
// ============================================================================
__global__ __launch_bounds__(256) void prep_kernel(
    const float* __restrict__ wm1, const float* __restrict__ wm2,
    const float* __restrict__ wc0, const float* __restrict__ wc1,
    const float* __restrict__ wc2, const float* __restrict__ wc3,
    const float* __restrict__ s,
    u16* __restrict__ wbuf, u16* __restrict__ xs, float* __restrict__ stats)
{
    const int bid = blockIdx.x;
    const int tid = threadIdx.x;
    if (bid < 2240) {
        // ---- weight conversion: [Cout][hi[Cin] | lo[Cin]] ----
        int i = bid * 256 + tid;
        float w; int r, k, Cin; size_t base;
        if (i < 8192) {                              // m1 padded [256][32]
            r = i >> 5; k = i & 31; Cin = 32; base = 0;
            w = (k < SDn) ? wm1[r * SDn + k] : 0.f;
        } else {
            int j = i - 8192;
            if (j < 131072)                    { r = j >> 8; k = j & 255; Cin = 256; base = 16384;   w = wm2[j]; }
            else if ((j -= 131072) < 262144)   { r = j >> 9; k = j & 511; Cin = 512; base = 278528;  w = wc0[j]; }
            else if ((j -= 262144) < 131072)   { r = j >> 9; k = j & 511; Cin = 512; base = 802816;  w = wc1[j]; }
            else if ((j -= 131072) < 32768)    { r = j >> 8; k = j & 255; Cin = 256; base = 1064960; w = wc2[j]; }
            else { j -= 32768;                   r = j >> 7; k = j & 127; Cin = 128; base = 1130496; w = wc3[j]; }
        }
        const size_t addr = base + (size_t)r * (2 * Cin) + k;
        u16 hi, lo; fsplit(w, hi, lo);
        wbuf[addr] = hi;
        wbuf[addr + Cin] = lo;
    } else if (bid < 2496) {
        // ---- normalize s[B,16,M] -> xs[N][64] (hi[32]|lo[32], upper 16 zero)
        const int b2 = bid - 2240;
        const int m = (b2 & 7) * 256 + tid;
        const int b = b2 >> 3;
        const float* sp = s + (size_t)b * SDn * Mn + m;
        float v[SDn]; float sq = 0.f;
#pragma unroll
        for (int c = 0; c < SDn; ++c) { v[c] = sp[(size_t)c * Mn]; sq += v[c] * v[c]; }
        const float r = 1.0f / sqrtf(sq);
        unsigned int uh[8], ul[8];
#pragma unroll
        for (int c = 0; c < 8; ++c) {
            u16 h0, l0, h1, l1;
            fsplit(v[2 * c] * r, h0, l0);
            fsplit(v[2 * c + 1] * r, h1, l1);
            uh[c] = (unsigned int)h0 | ((unsigned int)h1 << 16);
            ul[c] = (unsigned int)l0 | ((unsigned int)l1 << 16);
        }
        uint4* xp = (uint4*)(xs + (size_t)(b * Mn + m) * 64);
        xp[0] = make_uint4(uh[0], uh[1], uh[2], uh[3]);
        xp[1] = make_uint4(uh[4], uh[5], uh[6], uh[7]);
        xp[2] = make_uint4(0, 0, 0, 0);
        xp[3] = make_uint4(0, 0, 0, 0);
        xp[4] = make_uint4(ul[0], ul[1], ul[2], ul[3]);
        xp[5] = make_uint4(ul[4], ul[5], ul[6], ul[7]);
        xp[6] = make_uint4(0, 0, 0, 0);
        xp[7] = make_uint4(0, 0, 0, 0);
    } else {
        // ---- zero BN stats (4096 floats) ----
        float4 z4 = {0.f, 0.f, 0.f, 0.f};
        float4* sp4 = (float4*)stats;
#pragma unroll
        for (int k = 0; k < 4; ++k) sp4[tid * 4 + k] = z4;
    }
}

// ---- split fp16 MFMA GEMM, async staging, XCD remap, swizzled LDS ----------
// acc0 = Wh*Xh ; accL = Wh*Xl' + Wl'*Xh ; result = acc0 + accL/2048
// IBN=1: apply BN(scale,shift)+ReLU to B-frags between LDS read and MFMA
// (bit-identical to the former standalone bnrelu pass: same join/fma/max/split).
template<int RW, int CWv, int EPI, int MY, int IBN>
__global__ __launch_bounds__(256) void mfma_gemm(
    const u16* __restrict__ W, const u16* __restrict__ X, u16* __restrict__ Y,
    const float* __restrict__ bias, const float* __restrict__ zmod,
    const float* __restrict__ bnpin, float* __restrict__ stats, int Cout, int Cin)
{
    constexpr int BM = RW * 64, BN = CWv * 64;
    constexpr int ASEG = BM / 64, BSEG = BN / 64;
    constexpr int LMY = (MY == 1) ? 0 : (MY == 2) ? 1 : (MY == 4) ? 2 : 3;
    __shared__ __align__(16) u16 Ah[BM * 32], Al[BM * 32];
    __shared__ __align__(16) u16 Bh[BN * 32], Bl[BN * 32];
    __shared__ float sstat[(EPI == 2) ? (CWv * BM * 2) : 1];

    const int tid = threadIdx.x;
    const int wave = tid >> 6;
    const int lane = tid & 63;
    const int wm = wave & (RW - 1), wn = wave / RW;
    const int l15 = lane & 15, q = lane >> 4;
    const int lin = blockIdx.x;
    const int xcd = lin & 7;
    const int jj = lin >> 3;
    const int m0 = (jj & (MY - 1)) * BM;
    const int n0 = (xcd + ((jj >> LMY) << 3)) * BN;
    const int SW = 2 * Cin;

    f4v acc0[4][4], accL[4][4];
#pragma unroll
    for (int i = 0; i < 4; ++i)
#pragma unroll
        for (int j = 0; j < 4; ++j) {
            acc0[i][j] = (f4v){0.f, 0.f, 0.f, 0.f};
            accL[i][j] = (f4v){0.f, 0.f, 0.f, 0.f};
        }

    const int nsteps = Cin >> 5;
    for (int ks = 0; ks < nsteps; ++ks) {
        const int k0 = ks << 5;
        __syncthreads();   // previous iteration's frag reads done before overwrite
#pragma unroll
        for (int s = 0; s < ASEG; ++s) {
            const int flat = s * 256 + tid;
            const int row = flat >> 2;
            const int qs = (flat & 3) ^ ((row >> 1) & 3);   // swizzled source chunk
            const u16* ga = W + (size_t)(m0 + row) * SW + k0 + qs * 8;
            gll16(ga, Ah + flat * 8);
            gll16(ga + Cin, Al + flat * 8);
        }
#pragma unroll
        for (int s = 0; s < BSEG; ++s) {
            const int flat = s * 256 + tid;
            const int row = flat >> 2;
            const int qs = (flat & 3) ^ ((row >> 1) & 3);
            const u16* gb = X + (size_t)(n0 + row) * SW + k0 + qs * 8;
            gll16(gb, Bh + flat * 8);
            gll16(gb + Cin, Bl + flat * 8);
        }
        __syncthreads();   // drains vmcnt -> LDS tiles ready
        h8v afh[4], afl[4], bfh[4], bfl[4];
#pragma unroll
        for (int i = 0; i < 4; ++i) {
            const int ar = wm * 64 + i * 16 + l15;
            const int ao = ar * 32 + ((q ^ ((ar >> 1) & 3)) << 3);
            afh[i] = *(const h8v*)(Ah + ao);
            afl[i] = *(const h8v*)(Al + ao);
        }
#pragma unroll
        for (int j = 0; j < 4; ++j) {
            const int br = wn * 64 + j * 16 + l15;
            const int bo = br * 32 + ((q ^ ((br >> 1) & 3)) << 3);
            bfh[j] = *(const h8v*)(Bh + bo);
            bfl[j] = *(const h8v*)(Bl + bo);
        }
        if constexpr (IBN) {
            // frag elems are LOGICAL channels k0 + q*8 + e (read-side XOR
            // undoes the swizzle), uniform across l15 -> broadcast loads.
            const int kb = (k0 + q * 8) * 2;
            const float4 p0 = *(const float4*)(bnpin + kb);
            const float4 p1 = *(const float4*)(bnpin + kb + 4);
            const float4 p2 = *(const float4*)(bnpin + kb + 8);
            const float4 p3 = *(const float4*)(bnpin + kb + 12);
            const float sc8[8] = {p0.x, p0.z, p1.x, p1.z, p2.x, p2.z, p3.x, p3.z};
            const float sh8[8] = {p0.y, p0.w, p1.y, p1.w, p2.y, p2.w, p3.y, p3.w};
#pragma unroll
            for (int j = 0; j < 4; ++j) {
#pragma unroll
                for (int e = 0; e < 8; ++e) {
                    const float v = (float)bfh[j][e] + (float)bfl[j][e] * LSCI;
                    const float a = fmaxf(fmaf(v, sc8[e], sh8[e]), 0.f);
                    const fp16_t hh = (fp16_t)a;
                    bfh[j][e] = hh;
                    bfl[j][e] = (fp16_t)((a - (float)hh) * LSC);
                }
            }
        }
#pragma unroll
        for (int i = 0; i < 4; ++i)
#pragma unroll
            for (int j = 0; j < 4; ++j) {
                accL[i][j] = __builtin_amdgcn_mfma_f32_16x16x32_f16(afh[i], bfl[j], accL[i][j], 0, 0, 0);
                accL[i][j] = __builtin_amdgcn_mfma_f32_16x16x32_f16(afl[i], bfh[j], accL[i][j], 0, 0, 0);
                acc0[i][j] = __builtin_amdgcn_mfma_f32_16x16x32_f16(afh[i], bfh[j], acc0[i][j], 0, 0, 0);
            }
    }

    // ---- epilogue ----
    const int bb = n0 >> 11;
    const int SY = 2 * Cout;
#pragma unroll
    for (int i = 0; i < 4; ++i) {
        const int chb = m0 + wm * 64 + i * 16 + q * 4;
        const float4 bias4 = *(const float4*)(bias + chb);
        float z0 = 0.f, z1 = 0.f, z2 = 0.f, z3 = 0.f;
        if constexpr (EPI == 1) {
            const float4 z4 = *(const float4*)(zmod + bb * CWn + chb);
            z0 = z4.x; z1 = z4.y; z2 = z4.z; z3 = z4.w;
        }
        float ssum[4] = {0.f, 0.f, 0.f, 0.f}, ssq[4] = {0.f, 0.f, 0.f, 0.f};
#pragma unroll
        for (int j = 0; j < 4; ++j) {
            const int n = n0 + wn * 64 + j * 16 + l15;
            float v0 = fmaf(accL[i][j][0], LSCI, acc0[i][j][0]) + bias4.x;
            float v1 = fmaf(accL[i][j][1], LSCI, acc0[i][j][1]) + bias4.y;
            float v2 = fmaf(accL[i][j][2], LSCI, acc0[i][j][2]) + bias4.z;
            float v3 = fmaf(accL[i][j][3], LSCI, acc0[i][j][3]) + bias4.w;
            if constexpr (EPI == 0) {
                v0 = fmaxf(v0, 0.f); v1 = fmaxf(v1, 0.f); v2 = fmaxf(v2, 0.f); v3 = fmaxf(v3, 0.f);
            } else if constexpr (EPI == 1) {
                v0 = fminf(fmaxf(v0, -1.f), 1.f) * z0;
                v1 = fminf(fmaxf(v1, -1.f), 1.f) * z1;
                v2 = fminf(fmaxf(v2, -1.f), 1.f) * z2;
                v3 = fminf(fmaxf(v3, -1.f), 1.f) * z3;
            } else {
                ssum[0] += v0; ssum[1] += v1; ssum[2] += v2; ssum[3] += v3;
                ssq[0] += v0 * v0; ssq[1] += v1 * v1; ssq[2] += v2 * v2; ssq[3] += v3 * v3;
            }
            u16 h0, l0, h1, l1, h2, l2, h3, l3;
            fsplit(v0, h0, l0); fsplit(v1, h1, l1);
            fsplit(v2, h2, l2); fsplit(v3, h3, l3);
            ushort4 hv = {h0, h1, h2, h3};
            ushort4 lv = {l0, l1, l2, l3};
            u16* yp = Y + (size_t)n * SY + chb;
            *(ushort4*)yp = hv;
            *(ushort4*)(yp + Cout) = lv;
        }
        if constexpr (EPI == 2) {
#pragma unroll
            for (int r = 0; r < 4; ++r) {
#pragma unroll
                for (int d = 1; d < 16; d <<= 1) {
                    ssum[r] += __shfl_xor(ssum[r], d);
                    ssq[r]  += __shfl_xor(ssq[r], d);
                }
            }
            if (l15 == 0) {
                const int chl = wm * 64 + i * 16 + q * 4;
#pragma unroll
                for (int r = 0; r < 4; ++r) {
                    sstat[(wn * BM + chl + r) * 2]     = ssum[r];
                    sstat[(wn * BM + chl + r) * 2 + 1] = ssq[r];
                }
            }
        }
    }
    if constexpr (EPI == 2) {
        __syncthreads();
        if (tid < BM) {
            float s0 = 0.f, s1 = 0.f;
#pragma unroll
            for (int w = 0; w < CWv; ++w) {
                s0 += sstat[(w * BM + tid) * 2];
                s1 += sstat[(w * BM + tid) * 2 + 1];
            }
            atomicAdd(&stats[(m0 + tid) * 2], s0);
            atomicAdd(&stats[(m0 + tid) * 2 + 1], s1);
        }
    }
}

// ---- BN finalize: stats(sum,sumsq) -> (scale, shift) -----------------------
__global__ void finalize_kernel(const float* __restrict__ stats, const float* __restrict__ g,
                                const float* __restrict__ be, float* __restrict__ bnp, int C) {
    const int c = blockIdx.x * blockDim.x + threadIdx.x;
    if (c >= C) return;
    const float inv = 1.0f / (float)Nn;
    const float mean = stats[c * 2] * inv;
    const float var = stats[c * 2 + 1] * inv - mean * mean;
    const float sc = g[c] / sqrtf(var + EPSf);
    bnp[c * 2] = sc;
    bnp[c * 2 + 1] = fmaf(-mean, sc, be[c]);
}

// ---- final 64->3 conv (BN+ReLU on split input), vectorized loads -----------
__global__ __launch_bounds__(256) void finalconv_pm(
    const u16* __restrict__ y3, const float* __restrict__ bnp,
    const float* __restrict__ wout, const float* __restrict__ bout,
    float* __restrict__ pts)
{
    __shared__ float swo[3][64];
    __shared__ float ssc[64], ssh[64];
    const int tid = threadIdx.x;
    if (tid < 192) swo[tid / 64][tid % 64] = wout[tid];
    if (tid < 64) { ssc[tid] = bnp[tid * 2]; ssh[tid] = bnp[tid * 2 + 1]; }
    __syncthreads();
    const int n = blockIdx.x * 256 + tid;
    const uint4* yph = (const uint4*)(y3 + (size_t)n * 128);
    float d0 = bout[0], d1 = bout[1], d2 = bout[2];
#pragma unroll
    for (int cc = 0; cc < 8; ++cc) {
        const uint4 H = yph[cc];
        const uint4 L = yph[8 + cc];
        const unsigned hu[4] = {H.x, H.y, H.z, H.w};
        const unsigned lu[4] = {L.x, L.y, L.z, L.w};
#pragma unroll
        for (int e = 0; e < 4; ++e) {
            const int c = cc * 8 + e * 2;
            const float v0 = fjoin((u16)(hu[e] & 0xffff), (u16)(lu[e] & 0xffff));
            const float v1 = fjoin((u16)(hu[e] >> 16), (u16)(lu[e] >> 16));
            const float a0 = fmaxf(fmaf(v0, ssc[c], ssh[c]), 0.f);
            const float a1 = fmaxf(fmaf(v1, ssc[c + 1], ssh[c + 1]), 0.f);
            d0 = fmaf(a0, swo[0][c], d0); d0 = fmaf(a1, swo[0][c + 1], d0);
            d1 = fmaf(a0, swo[1][c], d1); d1 = fmaf(a1, swo[1][c + 1], d1);
            d2 = fmaf(a0, swo[2][c], d2); d2 = fmaf(a1, swo[2][c + 1], d2);
        }
    }
    float4 p = {d0, d1, d2, d0 * d0 + d1 * d1 + d2 * d2};
    *(float4*)(pts + (size_t)n * 4) = p;
}

// ---- graph filtering: 8 threads/point in one wave, branchless insert -------
__global__ __launch_bounds__(512) void knn_kernel(const float* __restrict__ pts,
                                                  float* __restrict__ out) {
    __shared__ __align__(16) float4 sp[Mn];   // 32 KB -> 4 blocks/CU (wave cap)
    const int b = blockIdx.y;
    const int tid = threadIdx.x;
    const float4* pb = (const float4*)pts + (size_t)b * Mn;
    for (int i = tid; i < Mn; i += 512) sp[i] = pb[i];
    __syncthreads();
    const int lane = tid & 63;
    const int wv = tid >> 6;                    // 0..7
    const int seg = lane & 7;                   // segment 0..7
    const int ptl = (wv << 3) | (lane >> 3);    // point-local 0..63
    const int m = blockIdx.x * 64 + ptl;
    const float4 p = sp[m];
    float bd[8]; int bi[8];
#pragma unroll
    for (int k = 0; k < 8; ++k) { bd[k] = 1e30f; bi[k] = 0x7fffffff; }
    const int nb = seg << 8;
    for (int t = 0; t < 256; ++t) {
        const int n = nb | ((t + seg) & 255);   // stagger start by seg (bank tiling)
        const float4 q = sp[n];
        const float dot = fmaf(p.x, q.x, fmaf(p.y, q.y, p.z * q.z));
        float d = fmaf(-2.f, dot, q.w);         // key = dist - p.w (monotone)
        d = (n == m) ? 1e30f : d;               // exclude self
        const bool ins = d < bd[7];
        bd[7] = ins ? d : bd[7];
        bi[7] = ins ? n : bi[7];
        cswapd(bd[6], bi[6], bd[7], bi[7]);
        cswapd(bd[5], bi[5], bd[6], bi[6]);
        cswapd(bd[4], bi[4], bd[5], bi[5]);
        cswapd(bd[3], bi[3], bd[4], bi[4]);
        cswapd(bd[2], bi[2], bd[3], bi[3]);
        cswapd(bd[1], bi[1], bd[2], bi[2]);
        cswapd(bd[0], bi[0], bd[1], bi[1]);
    }
    // 3 shuffle merge rounds: partner = lane ^ r (same point, r in {1,2,4})
#pragma unroll
    for (int r = 1; r <= 4; r <<= 1) {
        float od[8]; int oi[8];
#pragma unroll
        for (int k = 0; k < 8; ++k) {
            od[k] = __shfl_xor(bd[k], r);
            oi[k] = __shfl_xor(bi[k], r);
        }
        float md[8]; int mi[8];
#pragma unroll
        for (int k = 0; k < 8; ++k) {           // lowest-8 of union (bitonic)
            const float da = bd[k], db = od[7 - k];
            const int   ia = bi[k], ib = oi[7 - k];
            const bool bl = (db < da) || (db == da && ib < ia);
            md[k] = bl ? db : da; mi[k] = bl ? ib : ia;
        }
#define CSM(a, c) cswap(md[a], mi[a], md[c], mi[c])
        CSM(0,4); CSM(1,5); CSM(2,6); CSM(3,7);
        CSM(0,2); CSM(1,3); CSM(4,6); CSM(5,7);
        CSM(0,1); CSM(2,3); CSM(4,5); CSM(6,7);
#undef CSM
#pragma unroll
        for (int k = 0; k < 8; ++k) { bd[k] = md[k]; bi[k] = mi[k]; }
    }
    if (seg == 0) {
        float nx = 0.f, ny = 0.f, nz = 0.f;
#pragma unroll
        for (int k = 0; k < 8; ++k) { const float4 q = sp[bi[k]]; nx += q.x; ny += q.y; nz += q.z; }
        const float s8 = 0.125f;
        float* ob = out + (size_t)b * 3 * Mn;
        ob[m]          = 2.f * p.x - nx * s8;
        ob[Mn + m]     = 2.f * p.y - ny * s8;
        ob[2 * Mn + m] = 2.f * p.z - nz * s8;
    }
}

// ============================================================================
extern "C" void kernel_launch(void* const* d_in, const int* in_sizes, int n_in,
                              void* d_out, int out_size, void* d_ws, size_t ws_size,
                              hipStream_t stream)
{
    (void)in_sizes; (void)n_in; (void)out_size;
    const float* z     = (const float*)d_in[0];
    const float* s     = (const float*)d_in[1];
    const float* w_m1  = (const float*)d_in[2];
    const float* b_m1  = (const float*)d_in[3];
    const float* w_m2  = (const float*)d_in[4];
    const float* b_m2  = (const float*)d_in[5];
    const float* w_out = (const float*)d_in[6];
    const float* b_out = (const float*)d_in[7];
    const float* w_c[4]  = {(const float*)d_in[8],  (const float*)d_in[12], (const float*)d_in[16], (const float*)d_in[20]};
    const float* b_c[4]  = {(const float*)d_in[9],  (const float*)d_in[13], (const float*)d_in[17], (const float*)d_in[21]};
    const float* g_c[4]  = {(const float*)d_in[10], (const float*)d_in[14], (const float*)d_in[18], (const float*)d_in[22]};
    const float* be_c[4] = {(const float*)d_in[11], (const float*)d_in[15], (const float*)d_in[19], (const float*)d_in[23]};

    char* ws = (char*)d_ws;
    const size_t MB = 1024ull * 1024ull;
    float* outp = (float*)d_out;
    if (ws_size < 208 * MB) return;   // proven: harness provides >= 208 MiB

    // -------- split-fp16 MFMA path (peak 204 MiB) --------
    u16*   wbuf  = (u16*)ws;
    float* stats = (float*)(ws + 3 * MB);
    float* bnp   = stats + 4096;
    u16*   xs  = (u16*)(ws + 4 * MB);
    u16*   x1  = (u16*)(ws + 12 * MB);
    u16*   x2  = (u16*)(ws + 76 * MB);
    u16*   y0  = (u16*)(ws + 12 * MB);   // contiguous after both chunks (RAW)
    u16*   y0a = (u16*)(ws + 12 * MB);   // rows [0, 32K)
    u16*   y0b = (u16*)(ws + 76 * MB);   // rows [32K, 64K)
    u16*   y1  = (u16*)(ws + 140 * MB);  // RAW c1 output
    u16*   y2  = (u16*)(ws + 12 * MB);   // RAW c2 output
    u16*   y3  = (u16*)(ws + 76 * MB);   // RAW c3 output
    float* pts = (float*)(ws + 4 * MB);

    prep_kernel<<<2497, 256, 0, stream>>>(w_m1, w_m2, w_c[0], w_c[1], w_c[2], w_c[3], s, wbuf, xs, stats);
    // m1: [N][32] -> [N][256]  (Ntiles=512, MY=2 -> 1024 blocks)
    mfma_gemm<2, 2, 0, 2, 0><<<1024, 256, 0, stream>>>(wbuf, xs, x1, b_m1, nullptr, nullptr, nullptr, 256, 32);
    // m2: [N][256] -> [N][512] (Ntiles=512, MY=4 -> 2048 blocks)
    mfma_gemm<2, 2, 1, 4, 0><<<2048, 256, 0, stream>>>(wbuf + 16384, x1, x2, b_m2, z, nullptr, nullptr, 512, 256);
    // c0 a/b: rows halves      (Ntiles=256, MY=4 -> 1024 blocks each) -> RAW y0 + stats
    mfma_gemm<2, 2, 2, 4, 0><<<1024, 256, 0, stream>>>(wbuf + 278528, x2, y0a, b_c[0], nullptr, nullptr, stats + 0, 512, 512);
    mfma_gemm<2, 2, 2, 4, 0><<<1024, 256, 0, stream>>>(wbuf + 278528, x2 + (size_t)Hn * 1024, y0b, b_c[0], nullptr, nullptr, stats + 0, 512, 512);
    finalize_kernel<<<2, 256, 0, stream>>>(stats + 0, g_c[0], be_c[0], bnp + 0, 512);
    // c1: BN0+ReLU fused on B-input (bnp+0); RAW y1 + stats
    mfma_gemm<2, 2, 2, 2, 1><<<1024, 256, 0, stream>>>(wbuf + 802816, y0, y1, b_c[1], nullptr, bnp + 0, stats + 1024, 256, 512);
    finalize_kernel<<<1, 256, 0, stream>>>(stats + 1024, g_c[1], be_c[1], bnp + 1024, 256);
    // c2: BN1+ReLU fused on B-input (bnp+1024); RAW y2 + stats
    mfma_gemm<2, 2, 2, 1, 1><<<512, 256, 0, stream>>>(wbuf + 1064960, y1, y2, b_c[2], nullptr, bnp + 1024, stats + 2048, 128, 256);
    finalize_kernel<<<1, 128, 0, stream>>>(stats + 2048, g_c[2], be_c[2], bnp + 2048, 128);
    // c3: BN2+ReLU fused on B-input (bnp+2048); RAW y3 + stats
    mfma_gemm<1, 4, 2, 1, 1><<<256, 256, 0, stream>>>(wbuf + 1130496, y2, y3, b_c[3], nullptr, bnp + 2048, stats + 3072, 64, 128);
    finalize_kernel<<<1, 64, 0, stream>>>(stats + 3072, g_c[3], be_c[3], bnp + 3072, 64);
    finalconv_pm<<<Nn / 256, 256, 0, stream>>>(y3, bnp + 3072, w_out, b_out, pts);
    knn_kernel<<<dim3(Mn / 64, Bn), 512, 0, stream>>>(pts, outp);
}